// Round 4
// baseline (85.261 us; speedup 1.0000x reference)
//
#include <hip/hip_runtime.h>
#include <cfloat>

#define NFEAT 256
#define BATCH 4096
#define MTOT  16384
#define NSTRIP 8
#define STRIPW 2048
#define NHALF 32              // 2048 cols / 64-col halves
#define UMARGIN 0.75f

typedef __attribute__((ext_vector_type(8))) short bf16x8;
typedef __attribute__((ext_vector_type(4))) float f32x4;

#define GP(p)    ((const __attribute__((address_space(1))) void*)(p))
#define LDSP(p)  ((__attribute__((address_space(3))) void*)(p))

__device__ __forceinline__ unsigned bf16pack(float a, float b) {
    unsigned ua = __float_as_uint(a), ub = __float_as_uint(b);
    unsigned ra = (ua + 0x7fffu + ((ua >> 16) & 1u)) >> 16;
    unsigned rb = (ub + 0x7fffu + ((ub >> 16) & 1u)) >> 16;
    return ra | (rb << 16);
}

// ---------------------------------------------------------------------------
// Prep (fused): fp32->bf16 + squared norm for BOTH w (rows<MTOT) and xb.
// One wave per 256-feat row.
// ---------------------------------------------------------------------------
__global__ __launch_bounds__(256) void prep_kernel(const float* __restrict__ xb,
                                                   const float* __restrict__ w,
                                                   uint2* __restrict__ Abf,
                                                   uint2* __restrict__ Bbf,
                                                   float* __restrict__ a2,
                                                   float* __restrict__ b2) {
    int gid  = blockIdx.x * blockDim.x + threadIdx.x;
    int row  = gid >> 6;
    int lane = gid & 63;
    const float* src;
    uint2* dst;
    float* nrm;
    if (row < MTOT) {
        src = w + (size_t)row * NFEAT;  dst = Bbf + (size_t)row * 64;  nrm = b2 + row;
    } else {
        int r = row - MTOT;
        src = xb + (size_t)r * NFEAT;   dst = Abf + (size_t)r * 64;    nrm = a2 + r;
    }
    float4 v = ((const float4*)src)[lane];
    dst[lane] = make_uint2(bf16pack(v.x, v.y), bf16pack(v.z, v.w));
    float s = v.x * v.x + v.y * v.y + v.z * v.z + v.w * v.w;
    #pragma unroll
    for (int off = 32; off > 0; off >>= 1) s += __shfl_down(s, off);
    if (lane == 0) *nrm = s;
}

// ---------------------------------------------------------------------------
// Main: A-resident MFMA distance GEMM, counted-vmcnt prefetch pipeline.
// 256 blocks (1/CU), 512 thr (8 waves, 4m x 2n grid, 32x32 wave tile).
// LDS: A[128][256]bf16 64K | B0 32K | B1 32K | b2 strip 8K = 136 KB.
// min-dist == max-(dot - b2/2); per-lane top-2 with mantissa-packed ids.
// ---------------------------------------------------------------------------
__global__ __launch_bounds__(512, 1) void som_mfma_kernel(
        const unsigned short* __restrict__ Abf, const unsigned short* __restrict__ Bbf,
        const float* __restrict__ b2, float* __restrict__ part) {
    __shared__ char smem[139264];

    const int t = threadIdx.x, l = t & 63;
    const int wid = t >> 6, wm = wid >> 1, wc = wid & 1;
    const int strip = blockIdx.x & 7;            // strip == XCD (round-robin)
    const int m0 = (blockIdx.x >> 3) * 128;
    const int ns0 = strip * STRIPW;

    // staging geometry: thread t covers row (t>>5), in-row bytes (t&31)*16,
    // source pre-swizzled (^ (row&7)<<4), LDS dest linear; each round +8192 B.
    const int rowt = t >> 5;
    const int swzcol = ((t & 31) << 4) ^ ((rowt & 7) << 4);
    const char* gA = (const char*)Abf + (size_t)(m0 + rowt) * 512 + swzcol;
    const char* gB = (const char*)Bbf + (size_t)(ns0 + rowt) * 512 + swzcol;

    // prologue: A (8 rounds) + b2 strip (1) + B0 (4) + B1 (4)  -> 17 in flight
    #pragma unroll
    for (int i = 0; i < 8; ++i)
        __builtin_amdgcn_global_load_lds(GP(gA + i * 8192), LDSP(smem + t * 16 + i * 8192), 16, 0, 0);
    __builtin_amdgcn_global_load_lds(GP((const char*)b2 + (size_t)ns0 * 4 + t * 16),
                                     LDSP(smem + 131072 + t * 16), 16, 0, 0);
    #pragma unroll
    for (int i = 0; i < 4; ++i)
        __builtin_amdgcn_global_load_lds(GP(gB + i * 8192), LDSP(smem + 65536 + t * 16 + i * 8192), 16, 0, 0);
    #pragma unroll
    for (int i = 0; i < 4; ++i)
        __builtin_amdgcn_global_load_lds(GP(gB + 32768 + i * 8192), LDSP(smem + 98304 + t * 16 + i * 8192), 16, 0, 0);

    float r0[2][4], r1[2][4];
    #pragma unroll
    for (int m = 0; m < 2; ++m)
        #pragma unroll
        for (int j = 0; j < 4; ++j) { r0[m][j] = -FLT_MAX; r1[m][j] = -FLT_MAX; }

    for (int h = 0; h < NHALF; ++h) {
        // counted drain: B[h] complete (B[h+1] stays in flight), then barrier
        if (h < NHALF - 2) asm volatile("s_waitcnt vmcnt(4)" ::: "memory");
        else               asm volatile("s_waitcnt vmcnt(0)" ::: "memory");
        __builtin_amdgcn_s_barrier();
        asm volatile("" ::: "memory");

        const char* bufB = smem + 65536 + ((h & 1) << 15);
        const int cl = h * 64 + wc * 32 + (l & 15);
        const float b20 = -0.5f * *(const float*)(smem + 131072 + cl * 4);
        const float b21 = -0.5f * *(const float*)(smem + 131072 + cl * 4 + 64);

        f32x4 acc[2][2];
        #pragma unroll
        for (int m = 0; m < 2; ++m) {
            acc[m][0] = (f32x4){b20, b20, b20, b20};
            acc[m][1] = (f32x4){b21, b21, b21, b21};
        }

        #pragma unroll
        for (int kk = 0; kk < 8; ++kk) {
            const int swz = (kk * 64 + (l >> 4) * 16) ^ ((l & 7) << 4);
            bf16x8 af0 = *(const bf16x8*)(smem + (wm * 32 + (l & 15)) * 512 + swz);
            bf16x8 af1 = *(const bf16x8*)(smem + (wm * 32 + 16 + (l & 15)) * 512 + swz);
            bf16x8 bf0 = *(const bf16x8*)(bufB + (wc * 32 + (l & 15)) * 512 + swz);
            bf16x8 bf1 = *(const bf16x8*)(bufB + (wc * 32 + 16 + (l & 15)) * 512 + swz);
            acc[0][0] = __builtin_amdgcn_mfma_f32_16x16x32_bf16(af0, bf0, acc[0][0], 0, 0, 0);
            acc[0][1] = __builtin_amdgcn_mfma_f32_16x16x32_bf16(af0, bf1, acc[0][1], 0, 0, 0);
            acc[1][0] = __builtin_amdgcn_mfma_f32_16x16x32_bf16(af1, bf0, acc[1][0], 0, 0, 0);
            acc[1][1] = __builtin_amdgcn_mfma_f32_16x16x32_bf16(af1, bf1, acc[1][1], 0, 0, 0);
        }

        // top-2 accumulate: pack 6-bit id (h*2+n) into low mantissa bits
        #pragma unroll
        for (int n = 0; n < 2; ++n) {
            const unsigned idn = (unsigned)(h * 2 + n);
            #pragma unroll
            for (int m = 0; m < 2; ++m)
                #pragma unroll
                for (int j = 0; j < 4; ++j) {
                    float p = __uint_as_float((__float_as_uint(acc[m][n][j]) & 0xFFFFFFC0u) | idn);
                    float nr1 = __builtin_amdgcn_fmed3f(r0[m][j], r1[m][j], p);
                    r0[m][j] = fmaxf(r0[m][j], p);
                    r1[m][j] = nr1;
                }
        }

        asm volatile("" ::: "memory");
        __builtin_amdgcn_s_barrier();   // readers done with buf[h&1]
        asm volatile("" ::: "memory");
        if (h + 2 < NHALF) {
            const char* gBn = gB + (size_t)(h + 2) * 32768;
            const int dstb = 65536 + ((h & 1) << 15);
            #pragma unroll
            for (int i = 0; i < 4; ++i)
                __builtin_amdgcn_global_load_lds(GP(gBn + i * 8192),
                                                 LDSP(smem + dstb + t * 16 + i * 8192), 16, 0, 0);
        }
    }

    // ---- final merge: re-pack with 11-bit id, xor-merge over 16 lane-cols,
    //      cross-wave (wc) merge via LDS, store top-2 per (row, strip) ----
    asm volatile("" ::: "memory");
    __builtin_amdgcn_s_barrier();
    asm volatile("" ::: "memory");
    float* sm = (float*)smem;                    // [128][4] scratch (A region)
    #pragma unroll
    for (int m = 0; m < 2; ++m)
        #pragma unroll
        for (int j = 0; j < 4; ++j) {
            unsigned u0 = __float_as_uint(r0[m][j]);
            unsigned u1 = __float_as_uint(r1[m][j]);
            u0 = (u0 & 0xFFFFF800u) | ((u0 & 63u) << 5) | ((unsigned)wc << 4) | (unsigned)(l & 15);
            u1 = (u1 & 0xFFFFF800u) | ((u1 & 63u) << 5) | ((unsigned)wc << 4) | (unsigned)(l & 15);
            float v0 = __uint_as_float(u0), v1 = __uint_as_float(u1);
            #pragma unroll
            for (int off = 1; off < 16; off <<= 1) {
                float o0 = __shfl_xor(v0, off), o1 = __shfl_xor(v1, off);
                float nv1 = fmaxf(fminf(v0, o0), fmaxf(v1, o1));
                v0 = fmaxf(v0, o0);
                v1 = nv1;
            }
            if ((l & 15) == 0) {
                int row_l = wm * 32 + m * 16 + (l >> 4) * 4 + j;
                sm[row_l * 4 + wc * 2 + 0] = v0;
                sm[row_l * 4 + wc * 2 + 1] = v1;
            }
        }
    asm volatile("" ::: "memory");
    __builtin_amdgcn_s_barrier();
    asm volatile("" ::: "memory");
    if (t < 128) {
        float a0 = sm[t * 4 + 0], a1 = sm[t * 4 + 1];
        float c0 = sm[t * 4 + 2], c1 = sm[t * 4 + 3];
        float v0 = fmaxf(a0, c0);
        float v1 = fmaxf(fminf(a0, c0), fmaxf(a1, c1));
        float2* pp = (float2*)(part + ((size_t)(m0 + t) * NSTRIP + strip) * 2);
        *pp = make_float2(v0, v1);
    }
}

// ---------------------------------------------------------------------------
// Refine: one wave per row over 16 packed entries; exact fp32+sqrt recompute
// of candidates within margin; lexicographic (dist, idx) argmin.
// ---------------------------------------------------------------------------
__global__ __launch_bounds__(256) void refine_kernel(
        const float* __restrict__ xb, const float* __restrict__ w,
        const float* __restrict__ a2, const float* __restrict__ b2,
        const float* __restrict__ part, int* __restrict__ out) {
    const int t = threadIdx.x, l = t & 63;
    const int row = blockIdx.x * 4 + (t >> 6);

    const float* pr = part + (size_t)row * (NSTRIP * 2);
    float v = (l < NSTRIP * 2) ? pr[l] : -FLT_MAX;
    float mx = v;
    #pragma unroll
    for (int off = 1; off < 64; off <<= 1) mx = fmaxf(mx, __shfl_xor(mx, off));
    const float cut = mx - UMARGIN;

    unsigned long long key = ~0ull;
    if (l < NSTRIP * 2 && v >= cut) {
        unsigned b = __float_as_uint(v);
        int lane4 = b & 15, wcb = (b >> 4) & 1, hn = (b >> 5) & 63;
        int col = (l >> 1) * STRIPW + (hn >> 1) * 64 + wcb * 32 + (hn & 1) * 16 + lane4;
        const float4* xr = (const float4*)(xb + (size_t)row * NFEAT);
        const float4* wr = (const float4*)(w + (size_t)col * NFEAT);
        float s0 = 0.f, s1 = 0.f, s2 = 0.f, s3 = 0.f;
        #pragma unroll
        for (int k = 0; k < 16; ++k) {
            float4 x0 = xr[4 * k + 0], w0 = wr[4 * k + 0];
            float4 x1 = xr[4 * k + 1], w1 = wr[4 * k + 1];
            float4 x2 = xr[4 * k + 2], w2 = wr[4 * k + 2];
            float4 x3 = xr[4 * k + 3], w3 = wr[4 * k + 3];
            s0 += x0.x * w0.x + x0.y * w0.y + x0.z * w0.z + x0.w * w0.w;
            s1 += x1.x * w1.x + x1.y * w1.y + x1.z * w1.z + x1.w * w1.w;
            s2 += x2.x * w2.x + x2.y * w2.y + x2.z * w2.z + x2.w * w2.w;
            s3 += x3.x * w3.x + x3.y * w3.y + x3.z * w3.z + x3.w * w3.w;
        }
        float dot = (s0 + s1) + (s2 + s3);
        float dd = a2[row] + b2[col] - 2.f * dot;
        float s = sqrtf(fmaxf(dd, 0.f));
        key = ((unsigned long long)__float_as_uint(s) << 32) | (unsigned)col;
    }
    #pragma unroll
    for (int off = 1; off < 64; off <<= 1) {
        unsigned long long o = __shfl_xor(key, off);
        key = o < key ? o : key;
    }
    if (l == 0) {
        int idx = (int)(key & 0xffffffffu);
        out[2 * row]     = idx >> 7;
        out[2 * row + 1] = idx & 127;
    }
}

extern "C" void kernel_launch(void* const* d_in, const int* in_sizes, int n_in,
                              void* d_out, int out_size, void* d_ws, size_t ws_size,
                              hipStream_t stream) {
    const float* xb = (const float*)d_in[0];   // (4096, 256)
    const float* w  = (const float*)d_in[1];   // (16384, 256)
    int* out = (int*)d_out;

    char* ws = (char*)d_ws;
    unsigned short* Abf = (unsigned short*)ws;                 // 2 MB
    unsigned short* Bbf = (unsigned short*)(ws + (2u << 20));  // 8 MB
    float* a2   = (float*)(ws + (10u << 20));                  // 16 KB
    float* b2   = (float*)(ws + (10u << 20) + (64u << 10));    // 64 KB
    float* part = (float*)(ws + (10u << 20) + (128u << 10));   // 256 KB

    prep_kernel<<<((MTOT + BATCH) * 64) / 256, 256, 0, stream>>>(xb, w, (uint2*)Abf,
                                                                 (uint2*)Bbf, a2, b2);
    som_mfma_kernel<<<256, 512, 0, stream>>>(Abf, Bbf, b2, part);
    refine_kernel<<<BATCH / 4, 256, 0, stream>>>(xb, w, a2, b2, part, out);
}

// Round 5
// 75.990 us; speedup vs baseline: 1.1220x; 1.1220x over previous
//
#include <hip/hip_runtime.h>
#include <cfloat>

#define NFEAT 256
#define BATCH 4096
#define MTOT  16384
#define NSTRIP 8
#define STRIPW 2048
#define NH 16                 // h-steps per strip, 128 cols each
#define UMARGIN 0.75f

typedef __attribute__((ext_vector_type(8))) short bf16x8;
typedef __attribute__((ext_vector_type(4))) float f32x4;

#define GP(p)   ((const __attribute__((address_space(1))) void*)(p))
#define LDSP(p) ((__attribute__((address_space(3))) void*)(p))

__device__ __forceinline__ unsigned bf16pack(float a, float b) {
    unsigned ua = __float_as_uint(a), ub = __float_as_uint(b);
    unsigned ra = (ua + 0x7fffu + ((ua >> 16) & 1u)) >> 16;
    unsigned rb = (ub + 0x7fffu + ((ub >> 16) & 1u)) >> 16;
    return ra | (rb << 16);
}

// ---------------------------------------------------------------------------
// Prep (fused): fp32->bf16 + squared norm for both w and xb. 1 wave per row.
// ---------------------------------------------------------------------------
__global__ __launch_bounds__(256) void prep_kernel(const float* __restrict__ xb,
                                                   const float* __restrict__ w,
                                                   uint2* __restrict__ Abf,
                                                   uint2* __restrict__ Bbf,
                                                   float* __restrict__ a2,
                                                   float* __restrict__ b2) {
    int gid  = blockIdx.x * blockDim.x + threadIdx.x;
    int row  = gid >> 6;
    int lane = gid & 63;
    const float* src;
    uint2* dst;
    float* nrm;
    if (row < MTOT) {
        src = w + (size_t)row * NFEAT;  dst = Bbf + (size_t)row * 64;  nrm = b2 + row;
    } else {
        int r = row - MTOT;
        src = xb + (size_t)r * NFEAT;   dst = Abf + (size_t)r * 64;    nrm = a2 + r;
    }
    float4 v = ((const float4*)src)[lane];
    dst[lane] = make_uint2(bf16pack(v.x, v.y), bf16pack(v.z, v.w));
    float s = v.x * v.x + v.y * v.y + v.z * v.z + v.w * v.w;
    #pragma unroll
    for (int off = 32; off > 0; off >>= 1) s += __shfl_down(s, off);
    if (lane == 0) *nrm = s;
}

// ---------------------------------------------------------------------------
// Main: A-in-REGISTERS MFMA distance GEMM, counted-vmcnt B pipeline.
// 256 blocks (1/CU), 512 thr = 8 waves (2m x 4n), wave tile 64 rows x 32 cols.
// Each wave holds its 64-row A panel (full K=256) in 128 VGPRs, loaded once.
// LDS: B double-buffer 2x64 KB (128 cols full-K each) + b2 strip 8 KB.
// min-dist == max-(dot - b2/2); per-lane top-2 with mantissa-packed ids.
// ---------------------------------------------------------------------------
__global__ __launch_bounds__(512, 2) void som_mfma_kernel(
        const unsigned short* __restrict__ Abf, const unsigned short* __restrict__ Bbf,
        const float* __restrict__ b2, float* __restrict__ part) {
    __shared__ char smem[139264];   // B0 64K | B1 64K | b2 strip 8K

    const int t = threadIdx.x, l = t & 63;
    const int wid = t >> 6;
    const int wm = wid >> 2;        // 0..1  (row half)
    const int wc = wid & 3;         // 0..3  (col quarter of 128-col h-step)
    const int strip = blockIdx.x & 7;          // strip == XCD round-robin
    const int m0 = (blockIdx.x >> 3) * 128;
    const int ns0 = strip * STRIPW;

    // ---- prologue staging: b2 strip (1 op) + B0 (8) + B1 (8) per wave ----
    const int rowt = t >> 5;        // 0..15 (cols covered per 8K round)
    const int swzcol = ((t & 31) << 4) ^ ((rowt & 7) << 4);
    const char* gB = (const char*)Bbf + (size_t)(ns0 + rowt) * 512 + swzcol;

    __builtin_amdgcn_global_load_lds(GP((const char*)b2 + (size_t)ns0 * 4 + t * 16),
                                     LDSP(smem + 131072 + t * 16), 16, 0, 0);
    #pragma unroll
    for (int i = 0; i < 8; ++i)
        __builtin_amdgcn_global_load_lds(GP(gB + i * 8192),
                                         LDSP(smem + t * 16 + i * 8192), 16, 0, 0);
    #pragma unroll
    for (int i = 0; i < 8; ++i)
        __builtin_amdgcn_global_load_lds(GP(gB + 65536 + i * 8192),
                                         LDSP(smem + 65536 + t * 16 + i * 8192), 16, 0, 0);

    // ---- A panel -> registers (fragment layout, loaded straight from L2) ----
    // lane l, frag (m,kk): rows m0+wm*64+m*16+(l&15), bytes kk*64+(l>>4)*16
    const char* gA = (const char*)Abf
                   + (size_t)(m0 + wm * 64 + (l & 15)) * 512 + (l >> 4) * 16;
    bf16x8 afr[4][8];
    #pragma unroll
    for (int m = 0; m < 4; ++m)
        #pragma unroll
        for (int kk = 0; kk < 8; ++kk)
            afr[m][kk] = *(const bf16x8*)(gA + (size_t)m * 16 * 512 + kk * 64);

    float r0[4][4], r1[4][4];
    #pragma unroll
    for (int m = 0; m < 4; ++m)
        #pragma unroll
        for (int j = 0; j < 4; ++j) { r0[m][j] = -FLT_MAX; r1[m][j] = -FLT_MAX; }

    for (int h = 0; h < NH; ++h) {
        // counted drain: B(h) landed, B(h+1)'s 8 ops stay in flight
        if (h < NH - 1) asm volatile("s_waitcnt vmcnt(8)" ::: "memory");
        else            asm volatile("s_waitcnt vmcnt(0)" ::: "memory");
        __builtin_amdgcn_s_barrier();
        asm volatile("" ::: "memory");

        const char* bufB = smem + ((h & 1) << 16);
        const int c0 = h * 128 + wc * 32 + (l & 15);
        const float b20 = -0.5f * *(const float*)(smem + 131072 + c0 * 4);
        const float b21 = -0.5f * *(const float*)(smem + 131072 + c0 * 4 + 64);

        f32x4 acc[4][2];
        #pragma unroll
        for (int m = 0; m < 4; ++m) {
            acc[m][0] = (f32x4){b20, b20, b20, b20};
            acc[m][1] = (f32x4){b21, b21, b21, b21};
        }

        #pragma unroll
        for (int kk = 0; kk < 8; ++kk) {
            const int swz = (kk * 64 + (l >> 4) * 16) ^ ((l & 7) << 4);
            bf16x8 bf0 = *(const bf16x8*)(bufB + (wc * 32 + (l & 15)) * 512 + swz);
            bf16x8 bf1 = *(const bf16x8*)(bufB + (wc * 32 + 16 + (l & 15)) * 512 + swz);
            #pragma unroll
            for (int m = 0; m < 4; ++m) {
                acc[m][0] = __builtin_amdgcn_mfma_f32_16x16x32_bf16(afr[m][kk], bf0, acc[m][0], 0, 0, 0);
                acc[m][1] = __builtin_amdgcn_mfma_f32_16x16x32_bf16(afr[m][kk], bf1, acc[m][1], 0, 0, 0);
            }
        }

        // per-lane top-2: pack 5-bit id (h*2+n) into low mantissa bits
        #pragma unroll
        for (int n = 0; n < 2; ++n) {
            const unsigned idn = (unsigned)(h * 2 + n);
            #pragma unroll
            for (int m = 0; m < 4; ++m)
                #pragma unroll
                for (int j = 0; j < 4; ++j) {
                    float p = __uint_as_float((__float_as_uint(acc[m][n][j]) & 0xFFFFFFE0u) | idn);
                    float nr1 = __builtin_amdgcn_fmed3f(r0[m][j], r1[m][j], p);
                    r0[m][j] = fmaxf(r0[m][j], p);
                    r1[m][j] = nr1;
                }
        }

        asm volatile("" ::: "memory");
        __builtin_amdgcn_s_barrier();   // all readers done with buf (h&1)
        asm volatile("" ::: "memory");
        if (h + 2 < NH) {
            const char* gBn = gB + (size_t)(h + 2) * 65536;
            char* dst = smem + ((h & 1) << 16) + t * 16;
            #pragma unroll
            for (int i = 0; i < 8; ++i)
                __builtin_amdgcn_global_load_lds(GP(gBn + i * 8192),
                                                 LDSP(dst + i * 8192), 16, 0, 0);
        }
    }

    // ---- final merge: re-pack 11-bit id, xor-merge 16 lane-cols, cross-wave
    //      (wc) merge via LDS scratch (B0 region is dead), store top-2 ----
    float* sm = (float*)smem;           // [128][8]
    #pragma unroll
    for (int m = 0; m < 4; ++m)
        #pragma unroll
        for (int j = 0; j < 4; ++j) {
            unsigned u0 = __float_as_uint(r0[m][j]);
            unsigned u1 = __float_as_uint(r1[m][j]);
            u0 = (u0 & 0xFFFFF800u) | ((u0 & 31u) << 6) | ((unsigned)wc << 4) | (unsigned)(l & 15);
            u1 = (u1 & 0xFFFFF800u) | ((u1 & 31u) << 6) | ((unsigned)wc << 4) | (unsigned)(l & 15);
            float v0 = __uint_as_float(u0), v1 = __uint_as_float(u1);
            #pragma unroll
            for (int off = 1; off < 16; off <<= 1) {
                float o0 = __shfl_xor(v0, off), o1 = __shfl_xor(v1, off);
                float nv1 = fmaxf(fminf(v0, o0), fmaxf(v1, o1));
                v0 = fmaxf(v0, o0);
                v1 = nv1;
            }
            if ((l & 15) == 0) {
                int row_l = wm * 64 + m * 16 + (l >> 4) * 4 + j;
                sm[row_l * 8 + wc * 2 + 0] = v0;
                sm[row_l * 8 + wc * 2 + 1] = v1;
            }
        }
    __syncthreads();
    if (t < 128) {
        float V0 = -FLT_MAX, V1 = -FLT_MAX;
        #pragma unroll
        for (int q = 0; q < 4; ++q) {
            float a0 = sm[t * 8 + q * 2], a1 = sm[t * 8 + q * 2 + 1];
            float nv1 = fmaxf(fminf(V0, a0), fmaxf(V1, a1));
            V0 = fmaxf(V0, a0);
            V1 = nv1;
        }
        ((float2*)part)[(size_t)(m0 + t) * NSTRIP + strip] = make_float2(V0, V1);
    }
}

// ---------------------------------------------------------------------------
// Refine: 1 wave per row over 16 packed entries; exact fp32+sqrt recompute of
// candidates within margin; lexicographic (dist, idx) argmin.
// ---------------------------------------------------------------------------
__global__ __launch_bounds__(256) void refine_kernel(
        const float* __restrict__ xb, const float* __restrict__ w,
        const float* __restrict__ a2, const float* __restrict__ b2,
        const float* __restrict__ part, int* __restrict__ out) {
    const int t = threadIdx.x, l = t & 63;
    const int row = blockIdx.x * 4 + (t >> 6);

    const float* pr = part + (size_t)row * (NSTRIP * 2);
    float v = (l < NSTRIP * 2) ? pr[l] : -FLT_MAX;
    float mx = v;
    #pragma unroll
    for (int off = 1; off < 64; off <<= 1) mx = fmaxf(mx, __shfl_xor(mx, off));
    const float cut = mx - UMARGIN;

    unsigned long long key = ~0ull;
    if (l < NSTRIP * 2 && v >= cut) {
        unsigned b = __float_as_uint(v);
        int lane4 = b & 15, wcb = (b >> 4) & 3, inner = (b >> 6) & 31;
        int col = (l >> 1) * STRIPW + (inner >> 1) * 128 + wcb * 32
                + (inner & 1) * 16 + lane4;
        const float4* xr = (const float4*)(xb + (size_t)row * NFEAT);
        const float4* wr = (const float4*)(w + (size_t)col * NFEAT);
        float s0 = 0.f, s1 = 0.f, s2 = 0.f, s3 = 0.f;
        #pragma unroll
        for (int k = 0; k < 16; ++k) {
            float4 x0 = xr[4 * k + 0], w0 = wr[4 * k + 0];
            float4 x1 = xr[4 * k + 1], w1 = wr[4 * k + 1];
            float4 x2 = xr[4 * k + 2], w2 = wr[4 * k + 2];
            float4 x3 = xr[4 * k + 3], w3 = wr[4 * k + 3];
            s0 += x0.x * w0.x + x0.y * w0.y + x0.z * w0.z + x0.w * w0.w;
            s1 += x1.x * w1.x + x1.y * w1.y + x1.z * w1.z + x1.w * w1.w;
            s2 += x2.x * w2.x + x2.y * w2.y + x2.z * w2.z + x2.w * w2.w;
            s3 += x3.x * w3.x + x3.y * w3.y + x3.z * w3.z + x3.w * w3.w;
        }
        float dot = (s0 + s1) + (s2 + s3);
        float dd = a2[row] + b2[col] - 2.f * dot;
        float s = sqrtf(fmaxf(dd, 0.f));
        key = ((unsigned long long)__float_as_uint(s) << 32) | (unsigned)col;
    }
    #pragma unroll
    for (int off = 1; off < 64; off <<= 1) {
        unsigned long long o = __shfl_xor(key, off);
        key = o < key ? o : key;
    }
    if (l == 0) {
        int idx = (int)(key & 0xffffffffu);
        out[2 * row]     = idx >> 7;
        out[2 * row + 1] = idx & 127;
    }
}

extern "C" void kernel_launch(void* const* d_in, const int* in_sizes, int n_in,
                              void* d_out, int out_size, void* d_ws, size_t ws_size,
                              hipStream_t stream) {
    const float* xb = (const float*)d_in[0];   // (4096, 256)
    const float* w  = (const float*)d_in[1];   // (16384, 256)
    int* out = (int*)d_out;

    char* ws = (char*)d_ws;
    unsigned short* Abf = (unsigned short*)ws;                 // 2 MB
    unsigned short* Bbf = (unsigned short*)(ws + (2u << 20));  // 8 MB
    float* a2   = (float*)(ws + (10u << 20));                  // 16 KB
    float* b2   = (float*)(ws + (10u << 20) + (64u << 10));    // 64 KB
    float* part = (float*)(ws + (10u << 20) + (128u << 10));   // 256 KB

    prep_kernel<<<((MTOT + BATCH) * 64) / 256, 256, 0, stream>>>(xb, w, (uint2*)Abf,
                                                                 (uint2*)Bbf, a2, b2);
    som_mfma_kernel<<<256, 512, 0, stream>>>(Abf, Bbf, b2, part);
    refine_kernel<<<BATCH / 4, 256, 0, stream>>>(xb, w, a2, b2, part, out);
}

// Round 6
// 75.767 us; speedup vs baseline: 1.1253x; 1.0029x over previous
//
#include <hip/hip_runtime.h>
#include <cfloat>

#define NFEAT 256
#define BATCH 4096
#define MTOT  16384
#define NSTRIP 8
#define STRIPW 2048
#define NH 16                 // h-steps per strip, 128 cols each
#define UMARGIN 0.75f

typedef __attribute__((ext_vector_type(8))) short bf16x8;
typedef __attribute__((ext_vector_type(4))) float f32x4;

#define GP(p)   ((const __attribute__((address_space(1))) void*)(p))
#define LDSP(p) ((__attribute__((address_space(3))) void*)(p))

__device__ __forceinline__ unsigned bf16pack(float a, float b) {
    unsigned ua = __float_as_uint(a), ub = __float_as_uint(b);
    unsigned ra = (ua + 0x7fffu + ((ua >> 16) & 1u)) >> 16;
    unsigned rb = (ub + 0x7fffu + ((ub >> 16) & 1u)) >> 16;
    return ra | (rb << 16);
}

// ---------------------------------------------------------------------------
// Prep (fused): fp32->bf16 + squared norm for both w and xb. 1 wave per row.
// ---------------------------------------------------------------------------
__global__ __launch_bounds__(256) void prep_kernel(const float* __restrict__ xb,
                                                   const float* __restrict__ w,
                                                   uint2* __restrict__ Abf,
                                                   uint2* __restrict__ Bbf,
                                                   float* __restrict__ a2,
                                                   float* __restrict__ b2) {
    int gid  = blockIdx.x * blockDim.x + threadIdx.x;
    int row  = gid >> 6;
    int lane = gid & 63;
    const float* src;
    uint2* dst;
    float* nrm;
    if (row < MTOT) {
        src = w + (size_t)row * NFEAT;  dst = Bbf + (size_t)row * 64;  nrm = b2 + row;
    } else {
        int r = row - MTOT;
        src = xb + (size_t)r * NFEAT;   dst = Abf + (size_t)r * 64;    nrm = a2 + r;
    }
    float4 v = ((const float4*)src)[lane];
    dst[lane] = make_uint2(bf16pack(v.x, v.y), bf16pack(v.z, v.w));
    float s = v.x * v.x + v.y * v.y + v.z * v.z + v.w * v.w;
    #pragma unroll
    for (int off = 32; off > 0; off >>= 1) s += __shfl_down(s, off);
    if (lane == 0) *nrm = s;
}

// ---------------------------------------------------------------------------
// Main: A-in-REGISTERS MFMA distance GEMM, counted-vmcnt B pipeline.
// 256 blocks (1/CU), 512 thr = 8 waves (2m x 4n), wave tile 64 rows x 32 cols.
// A panel (64 rows x K=256) pinned in 128 VGPRs via asm laundering — the asm
// is the producer, so the compiler cannot rematerialize the loads in-loop
// (round-5 failure mode: VGPR=120 meant A was re-read from L2 every h-step).
// LDS: B double-buffer 2x64 KB + b2 strip 8 KB = 136 KB (1 block/CU).
// min-dist == max-(dot - b2/2); per-lane top-2 with mantissa-packed ids.
// ---------------------------------------------------------------------------
__global__ __launch_bounds__(512, 2) void som_mfma_kernel(
        const unsigned short* __restrict__ Abf, const unsigned short* __restrict__ Bbf,
        const float* __restrict__ b2, float* __restrict__ part) {
    __shared__ char smem[139264];   // B0 64K | B1 64K | b2 strip 8K

    const int t = threadIdx.x, l = t & 63;
    const int wid = t >> 6;
    const int wm = wid >> 2;        // 0..1  (row half)
    const int wc = wid & 3;         // 0..3  (col quarter of 128-col h-step)
    const int strip = blockIdx.x & 7;          // strip == XCD round-robin
    const int m0 = (blockIdx.x >> 3) * 128;
    const int ns0 = strip * STRIPW;

    // ---- A panel -> registers, issued FIRST (longest dependent chain) ----
    // lane l, frag (m,kk): rows m0+wm*64+m*16+(l&15), bytes kk*64+(l>>4)*16
    const char* gA = (const char*)Abf
                   + (size_t)(m0 + wm * 64 + (l & 15)) * 512 + (l >> 4) * 16;
    bf16x8 afr[4][8];
    #pragma unroll
    for (int m = 0; m < 4; ++m)
        #pragma unroll
        for (int kk = 0; kk < 8; ++kk)
            afr[m][kk] = *(const bf16x8*)(gA + (size_t)m * 16 * 512 + kk * 64);

    // ---- staging: b2 strip (1 op) + B0 (8) + B1 (8) per wave ----
    const int rowt = t >> 5;        // 0..15 (cols covered per 8K round)
    const int swzcol = ((t & 31) << 4) ^ ((rowt & 7) << 4);
    const char* gB = (const char*)Bbf + (size_t)(ns0 + rowt) * 512 + swzcol;

    __builtin_amdgcn_global_load_lds(GP((const char*)b2 + (size_t)ns0 * 4 + t * 16),
                                     LDSP(smem + 131072 + t * 16), 16, 0, 0);
    #pragma unroll
    for (int i = 0; i < 8; ++i)
        __builtin_amdgcn_global_load_lds(GP(gB + i * 8192),
                                         LDSP(smem + t * 16 + i * 8192), 16, 0, 0);
    #pragma unroll
    for (int i = 0; i < 8; ++i)
        __builtin_amdgcn_global_load_lds(GP(gB + 65536 + i * 8192),
                                         LDSP(smem + 65536 + t * 16 + i * 8192), 16, 0, 0);

    // ---- pin A in VGPRs (compiler waits A's vmcnt; B stays in flight) ----
    #pragma unroll
    for (int m = 0; m < 4; ++m)
        #pragma unroll
        for (int kk = 0; kk < 8; ++kk)
            asm volatile("" : "+v"(afr[m][kk]));

    float r0[4][4], r1[4][4];
    #pragma unroll
    for (int m = 0; m < 4; ++m)
        #pragma unroll
        for (int j = 0; j < 4; ++j) { r0[m][j] = -FLT_MAX; r1[m][j] = -FLT_MAX; }

    for (int h = 0; h < NH; ++h) {
        // counted drain: B(h) landed, B(h+1)'s 8 ops stay in flight
        if (h < NH - 1) asm volatile("s_waitcnt vmcnt(8)" ::: "memory");
        else            asm volatile("s_waitcnt vmcnt(0)" ::: "memory");
        __builtin_amdgcn_s_barrier();
        asm volatile("" ::: "memory");

        const char* bufB = smem + ((h & 1) << 16);
        const int c0 = h * 128 + wc * 32 + (l & 15);
        const float b20 = -0.5f * *(const float*)(smem + 131072 + c0 * 4);
        const float b21 = -0.5f * *(const float*)(smem + 131072 + c0 * 4 + 64);

        f32x4 acc[4][2];
        #pragma unroll
        for (int m = 0; m < 4; ++m) {
            acc[m][0] = (f32x4){b20, b20, b20, b20};
            acc[m][1] = (f32x4){b21, b21, b21, b21};
        }

        #pragma unroll
        for (int kk = 0; kk < 8; ++kk) {
            const int swz = (kk * 64 + (l >> 4) * 16) ^ ((l & 7) << 4);
            bf16x8 bf0 = *(const bf16x8*)(bufB + (wc * 32 + (l & 15)) * 512 + swz);
            bf16x8 bf1 = *(const bf16x8*)(bufB + (wc * 32 + 16 + (l & 15)) * 512 + swz);
            #pragma unroll
            for (int m = 0; m < 4; ++m) {
                acc[m][0] = __builtin_amdgcn_mfma_f32_16x16x32_bf16(afr[m][kk], bf0, acc[m][0], 0, 0, 0);
                acc[m][1] = __builtin_amdgcn_mfma_f32_16x16x32_bf16(afr[m][kk], bf1, acc[m][1], 0, 0, 0);
            }
        }

        // per-lane top-2: pack 5-bit id (h*2+n) into low mantissa bits
        #pragma unroll
        for (int n = 0; n < 2; ++n) {
            const unsigned idn = (unsigned)(h * 2 + n);
            #pragma unroll
            for (int m = 0; m < 4; ++m)
                #pragma unroll
                for (int j = 0; j < 4; ++j) {
                    float p = __uint_as_float((__float_as_uint(acc[m][n][j]) & 0xFFFFFFE0u) | idn);
                    float nr1 = __builtin_amdgcn_fmed3f(r0[m][j], r1[m][j], p);
                    r0[m][j] = fmaxf(r0[m][j], p);
                    r1[m][j] = nr1;
                }
        }

        asm volatile("" ::: "memory");
        __builtin_amdgcn_s_barrier();   // all readers done with buf (h&1)
        asm volatile("" ::: "memory");
        if (h + 2 < NH) {
            const char* gBn = gB + (size_t)(h + 2) * 65536;
            char* dst = smem + ((h & 1) << 16) + t * 16;
            #pragma unroll
            for (int i = 0; i < 8; ++i)
                __builtin_amdgcn_global_load_lds(GP(gBn + i * 8192),
                                                 LDSP(dst + i * 8192), 16, 0, 0);
        }
    }

    // ---- final merge: re-pack 11-bit id, xor-merge 16 lane-cols, cross-wave
    //      (wc) merge via LDS scratch (B0 region is dead), store top-2 ----
    float* sm = (float*)smem;           // [128][8]
    #pragma unroll
    for (int m = 0; m < 4; ++m)
        #pragma unroll
        for (int j = 0; j < 4; ++j) {
            unsigned u0 = __float_as_uint(r0[m][j]);
            unsigned u1 = __float_as_uint(r1[m][j]);
            u0 = (u0 & 0xFFFFF800u) | ((u0 & 31u) << 6) | ((unsigned)wc << 4) | (unsigned)(l & 15);
            u1 = (u1 & 0xFFFFF800u) | ((u1 & 31u) << 6) | ((unsigned)wc << 4) | (unsigned)(l & 15);
            float v0 = __uint_as_float(u0), v1 = __uint_as_float(u1);
            #pragma unroll
            for (int off = 1; off < 16; off <<= 1) {
                float o0 = __shfl_xor(v0, off), o1 = __shfl_xor(v1, off);
                float nv1 = fmaxf(fminf(v0, o0), fmaxf(v1, o1));
                v0 = fmaxf(v0, o0);
                v1 = nv1;
            }
            if ((l & 15) == 0) {
                int row_l = wm * 64 + m * 16 + (l >> 4) * 4 + j;
                sm[row_l * 8 + wc * 2 + 0] = v0;
                sm[row_l * 8 + wc * 2 + 1] = v1;
            }
        }
    __syncthreads();
    if (t < 128) {
        float V0 = -FLT_MAX, V1 = -FLT_MAX;
        #pragma unroll
        for (int q = 0; q < 4; ++q) {
            float a0 = sm[t * 8 + q * 2], a1 = sm[t * 8 + q * 2 + 1];
            float nv1 = fmaxf(fminf(V0, a0), fmaxf(V1, a1));
            V0 = fmaxf(V0, a0);
            V1 = nv1;
        }
        ((float2*)part)[(size_t)(m0 + t) * NSTRIP + strip] = make_float2(V0, V1);
    }
}

// ---------------------------------------------------------------------------
// Refine: 1 wave per row over 16 packed entries; exact fp32+sqrt recompute of
// candidates within margin; lexicographic (dist, idx) argmin.
// ---------------------------------------------------------------------------
__global__ __launch_bounds__(256) void refine_kernel(
        const float* __restrict__ xb, const float* __restrict__ w,
        const float* __restrict__ a2, const float* __restrict__ b2,
        const float* __restrict__ part, int* __restrict__ out) {
    const int t = threadIdx.x, l = t & 63;
    const int row = blockIdx.x * 4 + (t >> 6);

    const float* pr = part + (size_t)row * (NSTRIP * 2);
    float v = (l < NSTRIP * 2) ? pr[l] : -FLT_MAX;
    float mx = v;
    #pragma unroll
    for (int off = 1; off < 64; off <<= 1) mx = fmaxf(mx, __shfl_xor(mx, off));
    const float cut = mx - UMARGIN;

    unsigned long long key = ~0ull;
    if (l < NSTRIP * 2 && v >= cut) {
        unsigned b = __float_as_uint(v);
        int lane4 = b & 15, wcb = (b >> 4) & 3, inner = (b >> 6) & 31;
        int col = (l >> 1) * STRIPW + (inner >> 1) * 128 + wcb * 32
                + (inner & 1) * 16 + lane4;
        const float4* xr = (const float4*)(xb + (size_t)row * NFEAT);
        const float4* wr = (const float4*)(w + (size_t)col * NFEAT);
        float s0 = 0.f, s1 = 0.f, s2 = 0.f, s3 = 0.f;
        #pragma unroll
        for (int k = 0; k < 16; ++k) {
            float4 x0 = xr[4 * k + 0], w0 = wr[4 * k + 0];
            float4 x1 = xr[4 * k + 1], w1 = wr[4 * k + 1];
            float4 x2 = xr[4 * k + 2], w2 = wr[4 * k + 2];
            float4 x3 = xr[4 * k + 3], w3 = wr[4 * k + 3];
            s0 += x0.x * w0.x + x0.y * w0.y + x0.z * w0.z + x0.w * w0.w;
            s1 += x1.x * w1.x + x1.y * w1.y + x1.z * w1.z + x1.w * w1.w;
            s2 += x2.x * w2.x + x2.y * w2.y + x2.z * w2.z + x2.w * w2.w;
            s3 += x3.x * w3.x + x3.y * w3.y + x3.z * w3.z + x3.w * w3.w;
        }
        float dot = (s0 + s1) + (s2 + s3);
        float dd = a2[row] + b2[col] - 2.f * dot;
        float s = sqrtf(fmaxf(dd, 0.f));
        key = ((unsigned long long)__float_as_uint(s) << 32) | (unsigned)col;
    }
    #pragma unroll
    for (int off = 1; off < 64; off <<= 1) {
        unsigned long long o = __shfl_xor(key, off);
        key = o < key ? o : key;
    }
    if (l == 0) {
        int idx = (int)(key & 0xffffffffu);
        out[2 * row]     = idx >> 7;
        out[2 * row + 1] = idx & 127;
    }
}

extern "C" void kernel_launch(void* const* d_in, const int* in_sizes, int n_in,
                              void* d_out, int out_size, void* d_ws, size_t ws_size,
                              hipStream_t stream) {
    const float* xb = (const float*)d_in[0];   // (4096, 256)
    const float* w  = (const float*)d_in[1];   // (16384, 256)
    int* out = (int*)d_out;

    char* ws = (char*)d_ws;
    unsigned short* Abf = (unsigned short*)ws;                 // 2 MB
    unsigned short* Bbf = (unsigned short*)(ws + (2u << 20));  // 8 MB
    float* a2   = (float*)(ws + (10u << 20));                  // 16 KB
    float* b2   = (float*)(ws + (10u << 20) + (64u << 10));    // 64 KB
    float* part = (float*)(ws + (10u << 20) + (128u << 10));   // 256 KB

    prep_kernel<<<((MTOT + BATCH) * 64) / 256, 256, 0, stream>>>(xb, w, (uint2*)Abf,
                                                                 (uint2*)Bbf, a2, b2);
    som_mfma_kernel<<<256, 512, 0, stream>>>(Abf, Bbf, b2, part);
    refine_kernel<<<BATCH / 4, 256, 0, stream>>>(xb, w, a2, b2, part, out);
}